// Round 1
// baseline (326.224 us; speedup 1.0000x reference)
//
#include <hip/hip_runtime.h>

typedef float  f32x4  __attribute__((ext_vector_type(4)));
typedef __bf16 bf16x8 __attribute__((ext_vector_type(8)));

constexpr int D_IN   = 128;   // NUM_SLICES * MAX_RANK
constexpr int KMAX   = 64;    // MAX_RANK
constexpr int N_OUT  = 4096;
constexpr int NSLICE = 2;

// main-kernel tile: 64 rows x 512 cols, 8 waves (4 row-groups x 2 col-groups),
// wave tile 16x256 -> acc = 16 x f32x4 = 64 VGPRs/lane.
// Rationale: per block each physical output row gets a 2 KB contiguous write
// (vs 512 B at the old 128x128 tile) -> much better DRAM page locality for the
// permutation-scattered 256 MB output stream (the dominant traffic).
constexpr int BM = 64;
constexpr int BN = 512;
constexpr int THREADS = 512;

// workspace layout (ws is ~1 GiB; we use ~9 MB)
constexpr size_t WBF_OFF = 0;         // bf16 W  [num_lora][N_OUT][KMAX]    (4 MB)
constexpr size_t XBF_OFF = 8u << 20;  // bf16 X  [logical_row][slice][KMAX] (4 MB)

__device__ __forceinline__ unsigned short f2bf(float f) {
    unsigned u = __builtin_bit_cast(unsigned, f);
    u += 0x7fffu + ((u >> 16) & 1u);   // RNE (inputs finite)
    return (unsigned short)(u >> 16);
}
__device__ __forceinline__ unsigned pk2(float a, float b) {
    return (unsigned)f2bf(a) | ((unsigned)f2bf(b) << 16);
}

// ---- fused pre-pass: W f32->bf16 (blocks [0, wblocks)) and
//      X -> bf16 [logical_row][slice][KMAX] scaled/masked (remaining blocks).
// Both vectorized to 8 elems / thread (16 B stores). Running them in one
// launch lets the two halves overlap on the chip.
__global__ __launch_bounds__(256)
void conv_all(const float* __restrict__ w, uint4* __restrict__ wbf4, int wvec,
              const float* __restrict__ x,
              const int*   __restrict__ seg_indptr,
              const int*   __restrict__ weight_indices,
              const int*   __restrict__ lora_ranks,
              const float* __restrict__ scalings,
              const int*   __restrict__ permutation,
              uint4* __restrict__ xbf4,
              int num_segments, int m_tok, int wblocks)
{
    const int bid = blockIdx.x;
    if (bid < wblocks) {
        const int i = bid * 256 + threadIdx.x;           // 8 W elems each
        if (i >= wvec) return;
        const float* src = w + (size_t)i * 8;
        f32x4 a = *(const f32x4*)src;
        f32x4 b = *(const f32x4*)(src + 4);
        uint4 o;
        o.x = pk2(a.x, a.y); o.y = pk2(a.z, a.w);
        o.z = pk2(b.x, b.y); o.w = pk2(b.z, b.w);
        wbf4[i] = o;
    } else {
        const int idx = (bid - wblocks) * 256 + threadIdx.x;  // m_tok*16 threads
        if (idx >= m_tok * 16) return;
        const int l = idx >> 4;                 // logical row
        const int c = (idx & 15) * 8;           // first of 8 elems, 0..120
        const int j = c >> 6;                   // slice
        const int k = c & 63;

        int s = 0;
        for (int i = 0; i < num_segments; ++i)
            if (l >= seg_indptr[i] && l < seg_indptr[i + 1]) s = i;
        const int   wi   = weight_indices[s];
        const int   r    = lora_ranks[wi];
        const float scal = scalings[wi];

        const float* base = x + (size_t)permutation[l] * D_IN + j * r;
        uint4 o;
        if (k + 8 <= r && ((j * r) & 3) == 0) {         // aligned full-vector path
            f32x4 a = *(const f32x4*)(base + k);
            f32x4 b = *(const f32x4*)(base + k + 4);
            o.x = pk2(scal * a.x, scal * a.y); o.y = pk2(scal * a.z, scal * a.w);
            o.z = pk2(scal * b.x, scal * b.y); o.w = pk2(scal * b.z, scal * b.w);
        } else {
            float v[8];
            #pragma unroll
            for (int e = 0; e < 8; ++e)
                v[e] = (k + e < r) ? scal * base[k + e] : 0.f;
            o.x = pk2(v[0], v[1]); o.y = pk2(v[2], v[3]);
            o.z = pk2(v[4], v[5]); o.w = pk2(v[6], v[7]);
        }
        xbf4[idx] = o;
    }
}

// ---- main: fragments loaded straight from global (L2/L3-resident after the
// pre-pass), MFMA layout A[m=lane&15][k=quad*8+e], B[n=lane&15][k=quad*8+e],
// C col=lane&15 row=quad*4+reg. Assumes each BM-row block lies in one segment
// (segment boundaries are multiples of 2048; 64 | 2048) and each BN-col block
// in one slice (2048 % 512 == 0).
__global__ __launch_bounds__(THREADS, 4)
void lora_mfma(const __bf16* __restrict__ xbf,     // [l][slice][KMAX]
               const __bf16* __restrict__ wbf,     // [w][n][KMAX]
               const int*    __restrict__ seg_indptr,
               const int*    __restrict__ weight_indices,
               const int*    __restrict__ permutation,
               const int*    __restrict__ slice_offsets,
               float* __restrict__ out,
               int num_segments, int n_slices)
{
    __shared__ int Ps[BM];

    const int t    = threadIdx.x;
    const int row0 = blockIdx.y * BM;
    const int col0 = blockIdx.x * BN;

    if (t < BM) Ps[t] = permutation[row0 + t];
    __syncthreads();

    // adapter of this row-block's segment (block-uniform)
    int s = 0;
    for (int i = 0; i < num_segments; ++i)
        if (row0 >= seg_indptr[i] && row0 < seg_indptr[i + 1]) s = i;
    const int w = weight_indices[s];

    // slice of this col-block (block-uniform)
    int j = 0;
    for (int i = 1; i < n_slices; ++i) j += (col0 >= slice_offsets[i]);

    const int lane = t & 63;
    const int wv   = t >> 6;     // 0..7
    const int wn   = wv & 1;     // col group (256 cols)
    const int wm   = wv >> 1;    // row group (16 rows)
    const int quad = lane >> 4;
    const int l16  = lane & 15;

    const __bf16* __restrict__ Xb =
        xbf + ((size_t)(row0 + wm * 16 + l16) * NSLICE + j) * KMAX;
    const __bf16* __restrict__ Wb =
        wbf + ((size_t)w * N_OUT + col0 + wn * 256 + l16) * KMAX + quad * 8;

    f32x4 acc[16];
    #pragma unroll
    for (int nt = 0; nt < 16; ++nt) acc[nt] = {0.f, 0.f, 0.f, 0.f};

    const bf16x8 af0 = *(const bf16x8*)&Xb[quad * 8];        // k 0..31
    const bf16x8 af1 = *(const bf16x8*)&Xb[32 + quad * 8];   // k 32..63

    #pragma unroll
    for (int nt = 0; nt < 16; ++nt) {
        const __bf16* wp = Wb + (size_t)nt * 16 * KMAX;
        bf16x8 b0 = *(const bf16x8*)&wp[0];
        bf16x8 b1 = *(const bf16x8*)&wp[32];
        acc[nt] = __builtin_amdgcn_mfma_f32_16x16x32_bf16(af0, b0, acc[nt], 0, 0, 0);
        acc[nt] = __builtin_amdgcn_mfma_f32_16x16x32_bf16(af1, b1, acc[nt], 0, 0, 0);
    }

    // epilogue: per (quad,i) row, 16 consecutive 64B chunks along the row ->
    // 1 KB runs per wave, 2 KB per row per block.
    #pragma unroll
    for (int i = 0; i < 4; ++i) {
        const int m = wm * 16 + quad * 4 + i;
        float* op = &out[(size_t)Ps[m] * N_OUT + col0 + wn * 256 + l16];
        #pragma unroll
        for (int nt = 0; nt < 16; ++nt)
            op[nt * 16] = acc[nt][i];
    }
}

extern "C" void kernel_launch(void* const* d_in, const int* in_sizes, int n_in,
                              void* d_out, int out_size, void* d_ws, size_t ws_size,
                              hipStream_t stream) {
    (void)n_in; (void)out_size; (void)ws_size;
    const float* x              = (const float*)d_in[0];
    const float* weights        = (const float*)d_in[1];
    const int*   seg_indptr     = (const int*)d_in[2];
    const int*   weight_indices = (const int*)d_in[3];
    const int*   lora_ranks     = (const int*)d_in[4];
    const float* scalings       = (const float*)d_in[5];
    const int*   permutation    = (const int*)d_in[6];
    const int*   slice_offsets  = (const int*)d_in[7];
    float*       out            = (float*)d_out;

    const int num_segments = in_sizes[2] - 1;
    const int n_slices     = in_sizes[7] - 1;
    const int m_tok        = in_sizes[6];           // permutation has M entries
    const int w_elems      = in_sizes[1];           // num_lora*N_OUT*KMAX

    uint4* wbf = (uint4*)((char*)d_ws + WBF_OFF);
    uint4* xbf = (uint4*)((char*)d_ws + XBF_OFF);

    const int wvec    = w_elems / 8;                    // 8 elems per thread
    const int wblocks = (wvec + 255) / 256;
    const int xthr    = m_tok * 16;                     // 8 elems per thread
    const int xblocks = (xthr + 255) / 256;

    conv_all<<<wblocks + xblocks, 256, 0, stream>>>(
        weights, wbf, wvec, x, seg_indptr, weight_indices, lora_ranks,
        scalings, permutation, xbf, num_segments, m_tok, wblocks);

    dim3 grid(N_OUT / BN, m_tok / BM);
    lora_mfma<<<grid, THREADS, 0, stream>>>(
        (const __bf16*)xbf, (const __bf16*)wbf, seg_indptr, weight_indices,
        permutation, slice_offsets, out, num_segments, n_slices);
}

// Round 2
// 305.372 us; speedup vs baseline: 1.0683x; 1.0683x over previous
//
#include <hip/hip_runtime.h>

typedef float  f32x2v __attribute__((ext_vector_type(2)));
typedef float  f32x16 __attribute__((ext_vector_type(16)));
typedef __bf16 bf16x8 __attribute__((ext_vector_type(8)));

constexpr int D_IN   = 128;   // NUM_SLICES * MAX_RANK
constexpr int KMAX   = 64;    // MAX_RANK
constexpr int N_OUT  = 4096;
constexpr int NSLICE = 2;

constexpr int BM = 128;
constexpr int BN = 128;
constexpr int THREADS = 256;          // 4 waves, 2x2 of 64x64 wave tiles

// workspace layout (ws is ~1 GiB; we use ~9 MB)
constexpr size_t WBF_OFF = 0;         // bf16 W  [num_lora][N_OUT][KMAX]   (4 MB)
constexpr size_t XBF_OFF = 8u << 20;  // bf16 X  [logical_row][slice][KMAX] (4 MB)

__device__ __forceinline__ unsigned short f2bf(float f) {
    unsigned u = __builtin_bit_cast(unsigned, f);
    u += 0x7fffu + ((u >> 16) & 1u);   // RNE (inputs finite)
    return (unsigned short)(u >> 16);
}
__device__ __forceinline__ unsigned pk2(float a, float b) {
    return (unsigned)f2bf(a) | ((unsigned)f2bf(b) << 16);
}

// ---- pre-pass 1: W f32 -> bf16, same [n][k] layout -------------------------
__global__ __launch_bounds__(256)
void conv_w(const float* __restrict__ w, unsigned* __restrict__ wbf, int npairs) {
    int i = blockIdx.x * 256 + threadIdx.x;
    if (i >= npairs) return;
    f32x2v v = *(const f32x2v*)&w[(size_t)i * 2];
    wbf[i] = pk2(v.x, v.y);
}

// ---- pre-pass 2: X -> bf16 [logical_row][slice][KMAX], scaled/masked -------
__global__ __launch_bounds__(256)
void conv_x(const float* __restrict__ x,
            const int*   __restrict__ seg_indptr,
            const int*   __restrict__ weight_indices,
            const int*   __restrict__ lora_ranks,
            const float* __restrict__ scalings,
            const int*   __restrict__ permutation,
            unsigned* __restrict__ xbf,
            int num_segments, int m_tok)
{
    const int idx = blockIdx.x * 256 + threadIdx.x;          // m_tok*64 threads
    const int l   = idx >> 6;                                 // logical row
    if (l >= m_tok) return;
    const int c   = (idx & 63) * 2;                           // elem pair 0..126
    const int j   = c >> 6;                                   // slice
    const int k   = c & 63;

    int s = 0;
    for (int i = 0; i < num_segments; ++i)
        if (l >= seg_indptr[i] && l < seg_indptr[i + 1]) s = i;
    const int   w    = weight_indices[s];
    const int   r    = lora_ranks[w];
    const float scal = scalings[w];

    const int p = permutation[l];
    float v0 = 0.f, v1 = 0.f;
    if (k < r)     v0 = scal * x[(size_t)p * D_IN + j * r + k];
    if (k + 1 < r) v1 = scal * x[(size_t)p * D_IN + j * r + k + 1];
    xbf[idx] = pk2(v0, v1);
}

// ---- main: 32x32x16 fragments so every store instruction emits two FULL
// aligned 128 B lines (col=lane&31 contiguous per row-half), instead of the
// 16x16 layout's 4 x 64 B partial sectors. Geometry identical to the known-
// good 308 us version: BM=BN=128, 4 waves of 64x64 tiles, no LDS staging.
// A/B frag layout: [m|n = lane&31][k = (lane>>5)*8 + e]; C layout (verified):
// col = lane&31, row = (reg&3) + 8*(reg>>2) + 4*(lane>>5).
__global__ __launch_bounds__(THREADS, 4)
void lora_mfma(const __bf16* __restrict__ xbf,     // [l][slice][KMAX]
               const __bf16* __restrict__ wbf,     // [w][n][KMAX]
               const int*    __restrict__ seg_indptr,
               const int*    __restrict__ weight_indices,
               const int*    __restrict__ permutation,
               const int*    __restrict__ slice_offsets,
               float* __restrict__ out,
               int num_segments, int n_slices)
{
    __shared__ int Ps[BM];

    const int t    = threadIdx.x;
    const int row0 = blockIdx.y * BM;
    const int col0 = blockIdx.x * BN;

    if (t < BM) Ps[t] = permutation[row0 + t];
    __syncthreads();

    // adapter of this row-block's segment (block-uniform; 128 | 2048)
    int s = 0;
    for (int i = 0; i < num_segments; ++i)
        if (row0 >= seg_indptr[i] && row0 < seg_indptr[i + 1]) s = i;
    const int w = weight_indices[s];

    // slice of this col-block (block-uniform; 128 | 2048)
    int j = 0;
    for (int i = 1; i < n_slices; ++i) j += (col0 >= slice_offsets[i]);

    const int lane = t & 63;
    const int wv   = t >> 6;     // 0..3
    const int wm   = wv & 1;     // row half (64 rows)
    const int wn   = wv >> 1;    // col half (64 cols)
    const int half = lane >> 5;  // k-group / row-half selector
    const int l32  = lane & 31;

    const __bf16* __restrict__ Xb =
        xbf + ((size_t)(row0 + wm * 64 + l32) * NSLICE + j) * KMAX + half * 8;
    const __bf16* __restrict__ Wb =
        wbf + ((size_t)w * N_OUT + col0 + wn * 64 + l32) * KMAX + half * 8;

    f32x16 acc[2][2] = {};

    #pragma unroll
    for (int ks = 0; ks < 4; ++ks) {              // k = ks*16 + half*8 + e
        const int kof = ks * 16;
        bf16x8 a0 = *(const bf16x8*)&Xb[kof];                                 // rows +0..31
        bf16x8 a1 = *(const bf16x8*)&Xb[(size_t)32 * NSLICE * KMAX + kof];    // rows +32..63
        bf16x8 b0 = *(const bf16x8*)&Wb[kof];                                 // cols +0..31
        bf16x8 b1 = *(const bf16x8*)&Wb[(size_t)32 * KMAX + kof];             // cols +32..63
        acc[0][0] = __builtin_amdgcn_mfma_f32_32x32x16_bf16(a0, b0, acc[0][0], 0, 0, 0);
        acc[0][1] = __builtin_amdgcn_mfma_f32_32x32x16_bf16(a0, b1, acc[0][1], 0, 0, 0);
        acc[1][0] = __builtin_amdgcn_mfma_f32_32x32x16_bf16(a1, b0, acc[1][0], 0, 0, 0);
        acc[1][1] = __builtin_amdgcn_mfma_f32_32x32x16_bf16(a1, b1, acc[1][1], 0, 0, 0);
    }

    // epilogue: per (mt,reg) one physical row-base; the two nt stores are the
    // two 128 B lines of that row covered by this wave. Every store inst:
    // 2 rows x 32 lanes x 4 B = two complete aligned 128 B lines.
    #pragma unroll
    for (int mt = 0; mt < 2; ++mt) {
        #pragma unroll
        for (int reg = 0; reg < 16; ++reg) {
            const int m = wm * 64 + mt * 32 + (reg & 3) + 8 * (reg >> 2) + 4 * half;
            float* op = &out[(size_t)Ps[m] * N_OUT + col0 + wn * 64 + l32];
            op[0]  = acc[mt][0][reg];
            op[32] = acc[mt][1][reg];
        }
    }
}

extern "C" void kernel_launch(void* const* d_in, const int* in_sizes, int n_in,
                              void* d_out, int out_size, void* d_ws, size_t ws_size,
                              hipStream_t stream) {
    (void)n_in; (void)out_size; (void)ws_size;
    const float* x              = (const float*)d_in[0];
    const float* weights        = (const float*)d_in[1];
    const int*   seg_indptr     = (const int*)d_in[2];
    const int*   weight_indices = (const int*)d_in[3];
    const int*   lora_ranks     = (const int*)d_in[4];
    const float* scalings       = (const float*)d_in[5];
    const int*   permutation    = (const int*)d_in[6];
    const int*   slice_offsets  = (const int*)d_in[7];
    float*       out            = (float*)d_out;

    const int num_segments = in_sizes[2] - 1;
    const int n_slices     = in_sizes[7] - 1;
    const int m_tok        = in_sizes[6];           // permutation has M entries
    const int w_elems      = in_sizes[1];           // num_lora*N_OUT*KMAX

    unsigned* wbf = (unsigned*)((char*)d_ws + WBF_OFF);
    unsigned* xbf = (unsigned*)((char*)d_ws + XBF_OFF);

    const int wpairs = w_elems / 2;
    conv_w<<<(wpairs + 255) / 256, 256, 0, stream>>>(weights, wbf, wpairs);

    const int xthreads = m_tok * (NSLICE * KMAX / 2);
    conv_x<<<(xthreads + 255) / 256, 256, 0, stream>>>(
        x, seg_indptr, weight_indices, lora_ranks, scalings, permutation,
        xbf, num_segments, m_tok);

    dim3 grid(N_OUT / BN, m_tok / BM);
    lora_mfma<<<grid, THREADS, 0, stream>>>(
        (const __bf16*)xbf, (const __bf16*)wbf, seg_indptr, weight_indices,
        permutation, slice_offsets, out, num_segments, n_slices);
}